// Round 4
// baseline (191.017 us; speedup 1.0000x reference)
//
#include <hip/hip_runtime.h>

#define NCLS 80
#define VOTE_TH 0.65f
#define SOFT_THR 0.05f
#define ROWCAP 2048
#define MAXDET 100
#define NB 1281         // score bits [0x3D000000, 0x3F800000] >> 15
#define BINBASE 31232   // 0x3D000000 >> 15
#define CANDCAP 512
#define NCHUNK 6        // ceil(NB/256)

__device__ __forceinline__ int bin_of(unsigned int b) {
    int bin = (int)(b >> 15) - BINBASE;
    return bin < 0 ? 0 : (bin > NB - 1 ? NB - 1 : bin);
}

// Single-block fused pipeline: setup -> per-class greedy soft-vote -> top-100.
// One CU, 16 waves. All cross-phase state in LDS; rows spill to ws via L2.
__global__ __launch_bounds__(1024) void fused_kernel(
    const float* __restrict__ boxes,
    const float* __restrict__ scores,
    const int* __restrict__ labels,
    float* __restrict__ rows,     // ws: ROWCAP*6 floats
    float* __restrict__ out,
    int n)
{
#pragma clang fp contract(off)
    const int tid = threadIdx.x;
    const int lane = tid & 63;
    const int wave = tid >> 6;           // 0..15
    const unsigned long long lmask = (1ull << lane) - 1ull;
    const int chunks = (n + 63) >> 6;    // 32 for n=2048

    __shared__ int   idxL[NCLS * 64];    // 20480 B
    __shared__ float scoL[NCLS * 64];    // 20480 B
    __shared__ float sArr[ROWCAP];       //  8192 B (row scores for phase C)
    __shared__ int   ubuf[2560];         // 10240 B: counts[32][80] (A) | hist+cand (C)
    __shared__ int   kSh[NCLS];
    __shared__ float redmax[16];
    __shared__ float maxcSh;
    __shared__ int   rowcntSh, ncand, Jsh, carrySh, Tsh;
    __shared__ int   chunkSum[NCHUNK];

    // ---------------- Phase A: setup ----------------
    // zero d_out (tail slots must be 0)
    for (int i = tid; i < 6 * MAXDET; i += 1024) out[i] = 0.0f;

    // maxc = max(boxes) + 1 (order-independent max reduce)
    const float4* b4 = (const float4*)boxes;
    float m = -3.0e38f;
    for (int i = tid; i < n; i += 1024) {
        float4 v = b4[i];
        m = fmaxf(m, fmaxf(fmaxf(v.x, v.y), fmaxf(v.z, v.w)));
    }
#pragma unroll
    for (int d = 32; d; d >>= 1) m = fmaxf(m, __shfl_xor(m, d));
    if (lane == 0) redmax[wave] = m;

    int* counts = ubuf;                          // [chunk][cls]
    for (int i = tid; i < 32 * NCLS; i += 1024) counts[i] = 0;
    __syncthreads();
    if (tid == 0) {
        float mm = redmax[0];
        for (int w = 1; w < 16; ++w) mm = fmaxf(mm, redmax[w]);
        maxcSh = mm + 1.0f;
        rowcntSh = 0; ncand = 0; Tsh = 0;
    }

    // per-chunk stable ranks (wave w owns chunks w and w+16)
    int Ls[2] = {-1, -1}, ranks[2] = {0, 0}, gis[2] = {0, 0};
    for (int cc = 0; cc < 2; ++cc) {
        int c = wave + cc * 16;
        if (c >= chunks) break;
        int gi = c * 64 + lane;
        int L = (gi < n) ? labels[gi] : -1;
        int rank = 0, total = 0;
#pragma unroll
        for (int j = 0; j < 64; ++j) {
            int Lj = __shfl(L, j);
            bool e = (Lj == L);
            rank += (e && j < lane) ? 1 : 0;
            total += e ? 1 : 0;
        }
        if (L >= 0 && rank == total - 1) counts[c * NCLS + L] = total;
        Ls[cc] = L; ranks[cc] = rank; gis[cc] = gi;
    }
    __syncthreads();

    // per-class exclusive prefix over chunks
    if (tid < NCLS) {
        int running = 0;
#pragma unroll
        for (int c = 0; c < 32; ++c) {
            int t = counts[c * NCLS + tid];
            counts[c * NCLS + tid] = running;
            running += t;
        }
        kSh[tid] = (running > 64) ? 64 : running;
    }
    __syncthreads();

    // scatter into per-class lists (ascending original index order)
    for (int cc = 0; cc < 2; ++cc) {
        int c = wave + cc * 16;
        if (c >= chunks) break;
        int L = Ls[cc];
        if (L >= 0) {
            int pos = counts[c * NCLS + L] + ranks[cc];
            if (pos < 64) {
                idxL[L * 64 + pos] = gis[cc];
                scoL[L * 64 + pos] = scores[gis[cc]];
            }
        }
    }
    __syncthreads();

    // ---------------- Phase B: greedy soft-vote (wave w: classes w+16j) ----------------
    const float maxc = maxcSh;
    for (int jj = 0; jj < 5; ++jj) {
        const int cls = wave + 16 * jj;
        const int k = kSh[cls];
        const float off = (float)cls * maxc;   // contract(off): mul then add, like ref
        const float cls_f = (float)cls;

        float s = 0.0f; int gi = 0;
        if (lane < k) {
            gi = idxL[cls * 64 + lane];
            s  = scoL[cls * 64 + lane];
        }
        // stable rank by score desc (tie -> lower orig index); pads rank >= k
        int r = 0;
#pragma unroll
        for (int j = 0; j < 64; ++j) {
            float sj = __shfl(s, j);
            r += ((sj > s) || (sj == s && j < lane)) ? 1 : 0;
        }
        float x1 = 0.f, y1 = 0.f, x2 = 0.f, y2 = 0.f;
        if (lane < k) {
            float4 bb = b4[gi];
            x1 = bb.x + off; y1 = bb.y + off;
            x2 = bb.z + off; y2 = bb.w + off;
        }
        int addr = r * 4;   // scatter to sorted rank (push, within-wave)
        x1 = __int_as_float(__builtin_amdgcn_ds_permute(addr, __float_as_int(x1)));
        y1 = __int_as_float(__builtin_amdgcn_ds_permute(addr, __float_as_int(y1)));
        x2 = __int_as_float(__builtin_amdgcn_ds_permute(addr, __float_as_int(x2)));
        y2 = __int_as_float(__builtin_amdgcn_ds_permute(addr, __float_as_int(y2)));
        s  = __int_as_float(__builtin_amdgcn_ds_permute(addr, __float_as_int(s)));

        float area = (x2 - x1) * (y2 - y1);
        bool alive = lane < k;

        while (true) {
            unsigned long long avm = __ballot(alive);
            if (avm == 0ull) break;
            int pos = (int)__builtin_ctzll(avm);

            float cx1 = __shfl(x1, pos), cy1 = __shfl(y1, pos);
            float cx2 = __shfl(x2, pos), cy2 = __shfl(y2, pos);
            float carea = __shfl(area, pos), cs = __shfl(s, pos);

            float xx1 = fmaxf(cx1, x1), yy1 = fmaxf(cy1, y1);
            float xx2 = fminf(cx2, x2), yy2 = fminf(cy2, y2);
            float inter = fmaxf(xx2 - xx1, 0.0f) * fmaxf(yy2 - yy1, 0.0f);
            float iou = inter / ((carea + area) - inter);

            bool merge = alive && (iou >= VOTE_TH);
            unsigned long long mb = __ballot(merge);
            int nm = __popcll(mb);

            if (nm == 1) {
                // merged set = {leader}: sum-with-zeros == cur*cs exactly
                if (lane == 0) {
                    int slot = atomicAdd(&rowcntSh, 1);
                    if (slot < ROWCAP) {
                        float* rp = rows + slot * 6;
                        rp[0] = (cx1 * cs) / cs; rp[1] = (cy1 * cs) / cs;
                        rp[2] = (cx2 * cs) / cs; rp[3] = (cy2 * cs) / cs;
                        rp[4] = cs; rp[5] = cls_f;
                        sArr[slot] = cs;
                    }
                }
            } else {
                float msv = merge ? s : 0.0f;
                float w0 = msv, w1 = x1 * msv, w2 = y1 * msv, w3 = x2 * msv, w4 = y2 * msv;
#pragma unroll
                for (int d = 32; d; d >>= 1) {
                    w0 += __shfl_xor(w0, d);
                    w1 += __shfl_xor(w1, d);
                    w2 += __shfl_xor(w2, d);
                    w3 += __shfl_xor(w3, d);
                    w4 += __shfl_xor(w4, d);
                }
                float soft = s * (1.0f - iou);
                bool sv = merge && (soft >= SOFT_THR);
                unsigned long long sb = __ballot(sv);
                int nsoft = __popcll(sb);
                int slot = 0;
                if (lane == 0) slot = atomicAdd(&rowcntSh, 1 + nsoft);
                slot = __shfl(slot, 0);
                if (lane == 0 && slot < ROWCAP) {
                    float* rp = rows + slot * 6;
                    rp[0] = w1 / w0; rp[1] = w2 / w0;
                    rp[2] = w3 / w0; rp[3] = w4 / w0;
                    rp[4] = cs; rp[5] = cls_f;   // maxs == leader score (sorted desc)
                    sArr[slot] = cs;
                }
                if (sv) {
                    int wp = slot + 1 + __popcll(sb & lmask);
                    if (wp < ROWCAP) {
                        float* rp = rows + wp * 6;
                        rp[0] = x1; rp[1] = y1; rp[2] = x2; rp[3] = y2;
                        rp[4] = soft; rp[5] = cls_f;
                        sArr[wp] = soft;
                    }
                }
            }
            alive = alive && (iou < VOTE_TH);
        }
    }
    __syncthreads();

    // ---------------- Phase C: top-100 (histogram prune + exact rank) ----------------
    int cnt = rowcntSh;
    if (cnt > ROWCAP) cnt = ROWCAP;
    if (cnt <= 0) return;
    const int K = (cnt < MAXDET) ? cnt : MAXDET;

    int* hist = ubuf;                                          // NB ints
    unsigned long long* cand = (unsigned long long*)(ubuf + 1536); // CANDCAP keys
    for (int i = tid; i < NB; i += 1024) hist[i] = 0;
    __syncthreads();

    for (int i = tid; i < cnt; i += 1024)
        atomicAdd(&hist[bin_of(__float_as_uint(sArr[i]))], 1);
    __syncthreads();

    if (tid < NCHUNK) {
        int s = 0, base = tid * 256;
        int end = base + 256; if (end > NB) end = NB;
        for (int b = base; b < end; ++b) s += hist[b];
        chunkSum[tid] = s;
    }
    __syncthreads();

    if (tid < 64) {   // wave 0: J = max chunk with suffix >= K
        int suf = 0;
        if (tid < NCHUNK) for (int j = tid; j < NCHUNK; ++j) suf += chunkSum[j];
        unsigned long long bm = __ballot(tid < NCHUNK && suf >= K);
        int J = 63 - __builtin_clzll(bm);   // bm != 0: suffix(0) = cnt >= K
        if (tid == J) { Jsh = J; carrySh = suf - chunkSum[J]; }
    }
    __syncthreads();

    if (tid < 256) {   // fine scan within chunk J: T = max bin with suffix >= K
        int J = Jsh, b = J * 256 + tid;
        if (b < NB) {
            int end = J * 256 + 256; if (end > NB) end = NB;
            int suf = carrySh;
            for (int bb = b; bb < end; ++bb) suf += hist[bb];
            if (suf >= K) atomicMax(&Tsh, b);
        }
    }
    __syncthreads();
    const int T = Tsh;

    for (int i = tid; i < cnt; i += 1024) {
        unsigned int sb = __float_as_uint(sArr[i]);
        if (bin_of(sb) >= T) {
            int p = atomicAdd(&ncand, 1);
            if (p < CANDCAP)
                cand[p] = ((unsigned long long)sb << 32) |
                          (unsigned long long)(0xFFFFFFFFu - (unsigned int)i);
        }
    }
    __syncthreads();

    int nc = ncand; if (nc > CANDCAP) nc = CANDCAP;
    // key = scoreBits<<32 | ~slot: scores > 0 => uint order == float order;
    // tie -> smaller slot first (matches the reference's stable argsort).
    for (int j = tid; j < nc; j += 1024) {
        unsigned long long my = cand[j];
        int rank = 0;
        for (int l = 0; l < nc; ++l) rank += (cand[l] > my) ? 1 : 0;
        if (rank < K) {
            int i = (int)(0xFFFFFFFFu - (unsigned int)(my & 0xFFFFFFFFull));
            const float* rp = rows + i * 6;
            float lb = rp[5];
            float o = lb * maxc;               // mul then sub, like ref
            out[rank * 4 + 0] = rp[0] - o;
            out[rank * 4 + 1] = rp[1] - o;
            out[rank * 4 + 2] = rp[2] - o;
            out[rank * 4 + 3] = rp[3] - o;
            out[4 * MAXDET + rank] = rp[4];
            out[5 * MAXDET + rank] = lb;
        }
    }
}

extern "C" void kernel_launch(void* const* d_in, const int* in_sizes, int n_in,
                              void* d_out, int out_size, void* d_ws, size_t ws_size,
                              hipStream_t stream) {
    const float* boxes  = (const float*)d_in[0];
    const float* scores = (const float*)d_in[1];
    const int*   labels = (const int*)d_in[2];
    float* out  = (float*)d_out;
    float* rows = (float*)d_ws;          // ROWCAP*6 floats
    const int n = in_sizes[1];           // 2048

    hipLaunchKernelGGL(fused_kernel, dim3(1), dim3(1024), 0, stream,
                       boxes, scores, labels, rows, out, n);
}

// Round 6
// 96.258 us; speedup vs baseline: 1.9844x; 1.9844x over previous
//
#include <hip/hip_runtime.h>

#define NCLS 80
#define VOTE_TH 0.65f
#define SOFT_THR 0.05f
#define MAXDET 100
#define NB 1281         // score bits [0x3D000000, 0x3F800000] >> 15
#define BINBASE 31232   // 0x3D000000 >> 15
#define CANDCAP 512
#define SEG 21          // 61 lanes * 21 bins = 1281

__device__ __forceinline__ int bin_of(unsigned int b) {
    int bin = (int)(b >> 15) - BINBASE;
    return bin < 0 ? 0 : (bin > NB - 1 ? NB - 1 : bin);
}

// Kernel 1: 80 blocks x 1 wave, block = one class. Redundant per-block
// preamble (maxc + label compact) is free across 80 CUs. Rows land in a
// fixed per-class region (lcnt <= k <= 64 provably) -> no atomics at all.
__global__ __launch_bounds__(64, 1) void vote_kernel(
    const float* __restrict__ boxes,
    const float* __restrict__ scores,
    const int* __restrict__ labels,
    int* __restrict__ kCnt,      // [NCLS]
    float* __restrict__ sArrG,   // [NCLS*64] row scores
    float* __restrict__ rows,    // [NCLS*64*6]
    float* __restrict__ maxcP,
    int n)
{
#pragma clang fp contract(off)
    const int lane = threadIdx.x;
    const int cls = blockIdx.x;
    const unsigned long long lmask = (1ull << lane) - 1ull;
    const int chunks = (n + 63) >> 6;    // 32 for n=2048

    __shared__ int uidx[64];

    // ---- maxc = max(boxes)+1 (order-independent; batched loads for ILP) ----
    const float4* b4 = (const float4*)boxes;
    float m = -3.0e38f;
    for (int base = 0; base < chunks; base += 8) {
        float4 v[8];
#pragma unroll
        for (int u = 0; u < 8; ++u) {
            int c = base + u;
            v[u] = (c < chunks) ? b4[c * 64 + lane]
                                : make_float4(-3.0e38f, -3.0e38f, -3.0e38f, -3.0e38f);
        }
#pragma unroll
        for (int u = 0; u < 8; ++u)
            m = fmaxf(m, fmaxf(fmaxf(v[u].x, v[u].y), fmaxf(v[u].z, v[u].w)));
    }
#pragma unroll
    for (int d = 32; d; d >>= 1) m = fmaxf(m, __shfl_xor(m, d));
    const float maxc = m + 1.0f;
    if (cls == 0 && lane == 0) *maxcP = maxc;   // visible to kernel 2 at dispatch boundary
    const float off = (float)cls * maxc;   // contract(off): mul then add, like ref
    const float cls_f = (float)cls;

    // ---- my class's index list (ascending original index) ----
    int lab[32];
    for (int base = 0; base < 32; base += 8) {
#pragma unroll
        for (int u = 0; u < 8; ++u) {
            int c = base + u;
            lab[c] = (c < chunks) ? labels[c * 64 + lane] : -1;
        }
    }
    int k = 0;
    for (int c = 0; c < chunks; ++c) {
        bool p = (lab[c] == cls);
        unsigned long long b = __ballot(p);
        if (p) {
            int w = k + __popcll(b & lmask);
            if (w < 64) uidx[w] = c * 64 + lane;
        }
        k += __popcll(b);
    }
    if (k > 64) k = 64;
    __syncthreads();   // cheap for one wave; guarantees uidx write->read order

    float s = 0.0f;
    float4 bb = make_float4(0.f, 0.f, 0.f, 0.f);
    if (lane < k) {
        int gi = uidx[lane];
        s = scores[gi];
        bb = b4[gi];
    }

    // stable rank by score desc (tie -> lower list pos == lower orig index)
    int r = 0;
#pragma unroll
    for (int j = 0; j < 64; ++j) {
        float sj = __shfl(s, j);
        r += ((sj > s) || (sj == s && j < lane)) ? 1 : 0;
    }
    float x1 = 0.f, y1 = 0.f, x2 = 0.f, y2 = 0.f;
    if (lane < k) {
        x1 = bb.x + off; y1 = bb.y + off;
        x2 = bb.z + off; y2 = bb.w + off;
    }
    int addr = r * 4;   // scatter to sorted rank (push)
    x1 = __int_as_float(__builtin_amdgcn_ds_permute(addr, __float_as_int(x1)));
    y1 = __int_as_float(__builtin_amdgcn_ds_permute(addr, __float_as_int(y1)));
    x2 = __int_as_float(__builtin_amdgcn_ds_permute(addr, __float_as_int(x2)));
    y2 = __int_as_float(__builtin_amdgcn_ds_permute(addr, __float_as_int(y2)));
    s  = __int_as_float(__builtin_amdgcn_ds_permute(addr, __float_as_int(s)));

    float area = (x2 - x1) * (y2 - y1);
    bool alive = lane < k;

    float* rbase = rows + cls * 64 * 6;
    float* sbase = sArrG + cls * 64;
    int lcnt = 0;   // rows/class <= k <= 64 (leader iou=1 -> soft=0 -> never soft-row)
    while (true) {
        unsigned long long avm = __ballot(alive);
        if (avm == 0ull) break;
        int pos = (int)__builtin_ctzll(avm);

        float cx1 = __shfl(x1, pos), cy1 = __shfl(y1, pos);
        float cx2 = __shfl(x2, pos), cy2 = __shfl(y2, pos);
        float carea = __shfl(area, pos), cs = __shfl(s, pos);

        float xx1 = fmaxf(cx1, x1), yy1 = fmaxf(cy1, y1);
        float xx2 = fminf(cx2, x2), yy2 = fminf(cy2, y2);
        float inter = fmaxf(xx2 - xx1, 0.0f) * fmaxf(yy2 - yy1, 0.0f);
        float iou = inter / ((carea + area) - inter);

        bool merge = alive && (iou >= VOTE_TH);
        unsigned long long mb = __ballot(merge);
        int nm = __popcll(mb);

        if (nm == 1) {
            // merged set = {leader}: sum-with-zeros == cur*cs exactly
            if (lane == 0) {
                float* rp = rbase + lcnt * 6;
                rp[0] = (cx1 * cs) / cs; rp[1] = (cy1 * cs) / cs;
                rp[2] = (cx2 * cs) / cs; rp[3] = (cy2 * cs) / cs;
                rp[4] = cs; rp[5] = cls_f;
                sbase[lcnt] = cs;
            }
            lcnt += 1;
        } else {
            float msv = merge ? s : 0.0f;
            float w0 = msv, w1 = x1 * msv, w2 = y1 * msv, w3 = x2 * msv, w4 = y2 * msv;
#pragma unroll
            for (int d = 32; d; d >>= 1) {
                w0 += __shfl_xor(w0, d);
                w1 += __shfl_xor(w1, d);
                w2 += __shfl_xor(w2, d);
                w3 += __shfl_xor(w3, d);
                w4 += __shfl_xor(w4, d);
            }
            float soft = s * (1.0f - iou);
            bool sv = merge && (soft >= SOFT_THR);
            unsigned long long sb = __ballot(sv);
            int nsoft = __popcll(sb);
            if (lane == 0) {
                float* rp = rbase + lcnt * 6;
                rp[0] = w1 / w0; rp[1] = w2 / w0;
                rp[2] = w3 / w0; rp[3] = w4 / w0;
                rp[4] = cs; rp[5] = cls_f;   // maxs == leader score (sorted desc)
                sbase[lcnt] = cs;
            }
            if (sv) {
                int wp = lcnt + 1 + __popcll(sb & lmask);
                float* rp = rbase + wp * 6;
                rp[0] = x1; rp[1] = y1; rp[2] = x2; rp[3] = y2;
                rp[4] = soft; rp[5] = cls_f;
                sbase[wp] = soft;
            }
            lcnt += 1 + nsoft;
        }
        alive = alive && (iou < VOTE_TH);
    }

    if (lane == 0) kCnt[cls] = lcnt;
}

// Kernel 2: 1 block x 256. Top-100 via histogram prune + exact rank.
// key = scoreBits<<32 | ~rowIdx (scores>0 => uint order == float order;
// keys unique, so ordering is deterministic; ties impossible w/ continuous
// scores — verified absmax=0 across three different slot orders, r1-r3).
__global__ __launch_bounds__(256) void select_kernel(
    const float* __restrict__ rows,
    const float* __restrict__ sArrG,
    const int* __restrict__ kCnt,
    const float* __restrict__ maxcP,
    float* __restrict__ out)
{
#pragma clang fp contract(off)
    const int tid = threadIdx.x;
    const int lane = tid & 63;
    const int wave = tid >> 6;

    __shared__ int cnts[NCLS];
    __shared__ int hist[NB];
    __shared__ unsigned long long cand[CANDCAP];
    __shared__ int ncand_sh, T_sh, K_sh;

    for (int i = tid; i < 6 * MAXDET; i += 256) out[i] = 0.0f;
    if (tid < NCLS) cnts[tid] = kCnt[tid];
    for (int i = tid; i < NB; i += 256) hist[i] = 0;
    if (tid == 0) ncand_sh = 0;
    __syncthreads();

    for (int c = wave; c < NCLS; c += 4)
        if (lane < cnts[c])
            atomicAdd(&hist[bin_of(__float_as_uint(sArrG[c * 64 + lane]))], 1);
    __syncthreads();

    if (tid < 64) {   // wave 0: threshold bin T = max bin with suffix >= K
        int part = 0;
        if (lane < 61) {
            int b0 = lane * SEG;
            for (int b = b0; b < b0 + SEG; ++b) part += hist[b];
        }
        int suf = part;
#pragma unroll
        for (int d = 1; d < 64; d <<= 1) {
            int v = __shfl_down(suf, d);
            if (lane + d < 64) suf += v;
        }
        int cnt_total = __shfl(suf, 0);
        int K = (cnt_total < MAXDET) ? cnt_total : MAXDET;
        if (lane == 0) K_sh = K;
        unsigned long long bm = __ballot(suf >= K);   // lane0: suf=cnt_total>=K
        int L = 63 - __builtin_clzll(bm);
        if (lane == L) {
            int acc = suf - part;   // suffix of segments above L
            int T = 0;
            for (int b = L * SEG + SEG - 1; b >= L * SEG; --b) {
                acc += hist[b];
                if (acc >= K) { T = b; break; }
            }
            T_sh = T;
        }
    }
    __syncthreads();
    const int K = K_sh;
    if (K <= 0) return;
    const int T = T_sh;

    for (int c = wave; c < NCLS; c += 4) {
        if (lane < cnts[c]) {
            int idx = c * 64 + lane;
            unsigned int sb = __float_as_uint(sArrG[idx]);
            if (bin_of(sb) >= T) {
                int p = atomicAdd(&ncand_sh, 1);
                if (p < CANDCAP)
                    cand[p] = ((unsigned long long)sb << 32) |
                              (unsigned long long)(0xFFFFFFFFu - (unsigned int)idx);
            }
        }
    }
    __syncthreads();

    int nc = ncand_sh; if (nc > CANDCAP) nc = CANDCAP;
    const float maxc = *maxcP;
    for (int j = tid; j < nc; j += 256) {
        unsigned long long my = cand[j];
        int rank = 0;
        for (int l = 0; l < nc; ++l) rank += (cand[l] > my) ? 1 : 0;
        if (rank < K) {
            int idx = (int)(0xFFFFFFFFu - (unsigned int)(my & 0xFFFFFFFFull));
            const float* rp = rows + idx * 6;
            float lb = rp[5];
            float o = lb * maxc;               // mul then sub, like ref
            out[rank * 4 + 0] = rp[0] - o;
            out[rank * 4 + 1] = rp[1] - o;
            out[rank * 4 + 2] = rp[2] - o;
            out[rank * 4 + 3] = rp[3] - o;
            out[4 * MAXDET + rank] = rp[4];
            out[5 * MAXDET + rank] = lb;
        }
    }
}

extern "C" void kernel_launch(void* const* d_in, const int* in_sizes, int n_in,
                              void* d_out, int out_size, void* d_ws, size_t ws_size,
                              hipStream_t stream) {
    const float* boxes  = (const float*)d_in[0];
    const float* scores = (const float*)d_in[1];
    const int*   labels = (const int*)d_in[2];
    float* out = (float*)d_out;
    const int n = in_sizes[1];           // 2048

    char* ws = (char*)d_ws;
    int*   kCnt  = (int*)(ws + 0);                   // 80 ints (fully rewritten)
    float* maxcP = (float*)(ws + 384);
    float* sArrG = (float*)(ws + 512);               // 80*64 floats
    float* rows  = (float*)(ws + 512 + 20480);       // 80*64*6 floats

    hipLaunchKernelGGL(vote_kernel, dim3(NCLS), dim3(64), 0, stream,
                       boxes, scores, labels, kCnt, sArrG, rows, maxcP, n);
    hipLaunchKernelGGL(select_kernel, dim3(1), dim3(256), 0, stream,
                       rows, sArrG, kCnt, maxcP, out);
}